// Round 11
// baseline (1281.428 us; speedup 1.0000x reference)
//
#include <hip/hip_runtime.h>

// Problem constants
#define BB   512
#define CC   22
#define TT   1000
#define HH   64
#define NCLS 4
#define FCW  (TT * HH)       // 64000: W_fc row length
#define CH   64              // chunk length (time steps)
#define NCH  16              // 15 full chunks + 1 of 40
#define XPS  528             // xp LDS row stride bytes (64 uint2 + 16B pad -> bank spread)

typedef _Float16 f16;
typedef __attribute__((ext_vector_type(2))) _Float16 h2;
typedef __attribute__((ext_vector_type(8))) _Float16 f16x8;
typedef __attribute__((ext_vector_type(4))) float    f32x4;

union U16x8 { uint4 q; f16x8 h; f16 e[8]; };

__device__ __forceinline__ float sigm(float x) {
    float e = __expf(-x);
    return __builtin_amdgcn_rcpf(1.0f + e);
}
__device__ __forceinline__ float tanh_(float x) {
    float e = __expf(-2.0f * fabsf(x));   // (0,1], no overflow
    float r = (1.0f - e) * __builtin_amdgcn_rcpf(1.0f + e);
    return copysignf(r, x);
}
__device__ __forceinline__ h2 u2h(unsigned u) {
    union { unsigned u; h2 h; } c; c.u = u; return c.h;
}
__device__ __forceinline__ unsigned h2u(h2 h) {
    union { unsigned u; h2 h; } c; c.h = h; return c.u;
}
__device__ __forceinline__ unsigned pack2(float a, float b) {
    union { unsigned u; h2 h; } c;
    c.h = h2{(f16)a, (f16)b};
    return c.u;
}

// ---------------------------------------------------------------------------
// R15: single fused kernel. One wave per batch row (zero barriers), T in
// chunks of 64.
//
// Ledger driving this design:
//  * R13/R14 proved the serial step's ~500cyc stall is NOT h-LDS-roundtrip,
//    NOT W_fc, NOT xp-prefetch-depth. Stop chasing it; cut real costs.
//  * R11-R14's xproj split was a NET ZERO vs R4 (640 -> 655): the separate
//    kernel (~145us) + 262MB xp HBM roundtrip (FETCH 132MB in rec) ate the
//    serial-loop gain. The xp idea is right; going through HBM is wrong.
//  * Fix: compute xp PER CHUNK inside the kernel on the MATRIX pipe:
//    xp(256 x 64t) = W_ih(256x22) @ x(22x64t) as 64 MFMA/chunk (~5 cyc/step
//    equivalent vs 88 cyc/step of fdot2), packed f16 into LDS, bias added in
//    the serial loop. Fragment layouts are R8's HW-verified ones:
//      A: m=lane&15, k=8*(lane>>4)+e;  B: n=lane&15, k=8*(lane>>4)+e
//      D: n=lane&15, m=4*(lane>>4)+reg
//    D-tile is single-gate (gate g = tile>>2), so lane packs (i,f),(g,o)
//    pairs for 4 hids of one t -> 4 ds_write_b64 into xpb.
//  * Serial loop: LDS-only (1 b64 xp + 8 broadcast b128 h + 1 b16 h-write),
//    128 fdot2, acts. hst doubles as h-broadcast and FC history (R13).
//  * Chunk-end batched FC off the serial path (R13).
// LDS 46KB -> 2-3 blocks/CU. No workspace, no second dispatch.
// ---------------------------------------------------------------------------
__global__ __launch_bounds__(64, 1) void lstm_fused(
    const float* __restrict__ x,     // [B, C, T]
    const float* __restrict__ W_ih,  // [4H, C]
    const float* __restrict__ W_hh,  // [4H, H]
    const float* __restrict__ b_ih,  // [4H]
    const float* __restrict__ b_hh,  // [4H]
    const float* __restrict__ W_fc,  // [NCLS, T*H]
    const float* __restrict__ b_fc,  // [NCLS]
    float* __restrict__ out)         // [B, NCLS]
{
    __shared__ __align__(16) f16  xs[CH][32];      // 4 KB: x chunk (ch padded to 32)
    __shared__ __align__(16) char xpb[CH * XPS];   // 33 KB: xp chunk, uint2 per (t,hid)
    __shared__ __align__(16) f16  hst[CH][HH];     // 8 KB: h history + broadcast

    const int lane = threadIdx.x;    // hidden unit in serial phase
    const int r    = blockIdx.x;     // batch row
    const int q    = lane >> 4;      // MFMA lane fields
    const int c    = lane & 15;

    // ---- resident recurrent weights (128 regs) + folded bias, pinned ----
    unsigned whh[4][32];
    float bias[4];
    #pragma unroll
    for (int g = 0; g < 4; ++g) {
        const int row = g * HH + lane;
        const float* wr = W_hh + row * HH;
        #pragma unroll
        for (int k = 0; k < 32; ++k)
            whh[g][k] = pack2(wr[2 * k], wr[2 * k + 1]);
        bias[g] = b_ih[row] + b_hh[row];
    }
    #pragma unroll
    for (int g = 0; g < 4; ++g) {
        #pragma unroll
        for (int k = 0; k < 32; ++k) asm volatile("" : "+v"(whh[g][k]));
        asm volatile("" : "+v"(bias[g]));
    }

    hst[CH - 1][lane] = (f16)0.0f;   // h_0: read by chunk 0, tt=0 (own-wave DS)
    float cst = 0.0f;
    float fc0 = 0.f, fc1 = 0.f, fc2 = 0.f, fc3 = 0.f;
    const float* xrow = x + (size_t)r * (CC * TT);

    for (int ch = 0; ch < NCH; ++ch) {
        const int T0 = ch * CH;
        const int Lc = (T0 + CH <= TT) ? CH : (TT - T0);

        // ---- stage x chunk into LDS: lane <-> t, one iteration ----
        {
            const int t = lane;
            union { h2 h[16]; uint4 qq[4]; } U;
            if (t < Lc) {
                const float* gx = xrow + T0 + t;
                #pragma unroll
                for (int k = 0; k < 11; ++k)
                    U.h[k] = h2{(f16)gx[(2 * k) * TT], (f16)gx[(2 * k + 1) * TT]};
                #pragma unroll
                for (int k = 11; k < 16; ++k) U.h[k] = h2{(f16)0.0f, (f16)0.0f};
            } else {
                #pragma unroll
                for (int k = 0; k < 16; ++k) U.h[k] = h2{(f16)0.0f, (f16)0.0f};
            }
            uint4* dst = (uint4*)&xs[t][0];
            dst[0] = U.qq[0]; dst[1] = U.qq[1]; dst[2] = U.qq[2]; dst[3] = U.qq[3];
        }

        // ---- x-projection GEMM into xpb (matrix pipe, off serial path) ----
        #pragma unroll
        for (int mt = 0; mt < 4; ++mt) {            // hid-group: hids 16mt..16mt+15
            // A-fragments for the 4 gate tiles (rows g*64 + 16mt + c)
            f16x8 Afr[4];
            #pragma unroll
            for (int g = 0; g < 4; ++g) {
                const float* wbase = W_ih + (size_t)(g * HH + 16 * mt + c) * CC;
                U16x8 u;
                #pragma unroll
                for (int e = 0; e < 8; ++e) {
                    const int chn = 8 * q + e;
                    u.e[e] = (f16)(chn < CC ? wbase[chn] : 0.0f);
                }
                Afr[g] = u.h;
            }
            #pragma unroll
            for (int tg = 0; tg < 4; ++tg) {        // t-group: t = 16tg + c
                U16x8 Bf;
                Bf.q = *(const uint4*)&xs[16 * tg + c][8 * q];
                const f32x4 z = {0.f, 0.f, 0.f, 0.f};
                f32x4 Di = __builtin_amdgcn_mfma_f32_16x16x32_f16(Afr[0], Bf.h, z, 0, 0, 0);
                f32x4 Df = __builtin_amdgcn_mfma_f32_16x16x32_f16(Afr[1], Bf.h, z, 0, 0, 0);
                f32x4 Dg = __builtin_amdgcn_mfma_f32_16x16x32_f16(Afr[2], Bf.h, z, 0, 0, 0);
                f32x4 Do = __builtin_amdgcn_mfma_f32_16x16x32_f16(Afr[3], Bf.h, z, 0, 0, 0);
                // write pairs for t = 16tg+c, hids 16mt+4q+r
                char* wp = xpb + (size_t)(16 * tg + c) * XPS + (16 * mt + 4 * q) * 8;
                #pragma unroll
                for (int rr = 0; rr < 4; ++rr) {
                    uint2 v;
                    v.x = pack2(Di[rr], Df[rr]);    // (i, f)
                    v.y = pack2(Dg[rr], Do[rr]);    // (g, o)
                    *(uint2*)(wp + rr * 8) = v;
                }
            }
        }
        // single wave: DS pipe is in-order; serial reads below see the writes

        // ---- serial recurrence over the chunk (LDS-only step) ----
        for (int tt = 0; tt < Lc; ++tt) {
            const int pr = (tt == 0) ? (CH - 1) : tt - 1;

            // xp for this step: one ds_read_b64
            const uint2 xv = *(const uint2*)(xpb + (size_t)tt * XPS + lane * 8);
            const h2 pif = u2h(xv.x), pgo = u2h(xv.y);
            float a0 = bias[0] + (float)pif[0];
            float a1 = bias[1] + (float)pif[1];
            float a2 = bias[2] + (float)pgo[0];
            float a3 = bias[3] + (float)pgo[1];

            // h broadcast, two halves (halves live H registers)
            const uint4* hr = (const uint4*)&hst[pr][0];
            {
                union { uint4 qq[4]; h2 h[16]; } H;
                H.qq[0] = hr[0]; H.qq[1] = hr[1]; H.qq[2] = hr[2]; H.qq[3] = hr[3];
                #pragma unroll
                for (int k = 0; k < 16; ++k) {
                    a0 = __builtin_amdgcn_fdot2(H.h[k], u2h(whh[0][k]), a0, false);
                    a1 = __builtin_amdgcn_fdot2(H.h[k], u2h(whh[1][k]), a1, false);
                    a2 = __builtin_amdgcn_fdot2(H.h[k], u2h(whh[2][k]), a2, false);
                    a3 = __builtin_amdgcn_fdot2(H.h[k], u2h(whh[3][k]), a3, false);
                }
            }
            {
                union { uint4 qq[4]; h2 h[16]; } H;
                H.qq[0] = hr[4]; H.qq[1] = hr[5]; H.qq[2] = hr[6]; H.qq[3] = hr[7];
                #pragma unroll
                for (int k = 0; k < 16; ++k) {
                    a0 = __builtin_amdgcn_fdot2(H.h[k], u2h(whh[0][16 + k]), a0, false);
                    a1 = __builtin_amdgcn_fdot2(H.h[k], u2h(whh[1][16 + k]), a1, false);
                    a2 = __builtin_amdgcn_fdot2(H.h[k], u2h(whh[2][16 + k]), a2, false);
                    a3 = __builtin_amdgcn_fdot2(H.h[k], u2h(whh[3][16 + k]), a3, false);
                }
            }

            // lane-local LSTM update
            const float iv = sigm(a0), fv = sigm(a1);
            const float gv = tanh_(a2), ov = sigm(a3);
            cst = fv * cst + iv * gv;
            const float h = ov * tanh_(cst);

            // publish h (history row tt = broadcast source for tt+1)
            hst[tt][lane] = (f16)h;
        }

        // ---- chunk-end batched FC (off the serial path, coalesced) ----
        const float* w0 = W_fc + 0 * FCW + (size_t)T0 * HH + lane;
        const float* w1 = W_fc + 1 * FCW + (size_t)T0 * HH + lane;
        const float* w2 = W_fc + 2 * FCW + (size_t)T0 * HH + lane;
        const float* w3 = W_fc + 3 * FCW + (size_t)T0 * HH + lane;
        for (int tt = 0; tt < Lc; ++tt) {
            const float hv = (float)hst[tt][lane];
            fc0 += hv * w0[(size_t)tt * HH];
            fc1 += hv * w1[(size_t)tt * HH];
            fc2 += hv * w2[(size_t)tt * HH];
            fc3 += hv * w3[(size_t)tt * HH];
        }
    }

    // ---- FC reduce over hid (wave shuffle) + softmax ----
    #pragma unroll
    for (int off = 32; off; off >>= 1) {
        fc0 += __shfl_down(fc0, off);
        fc1 += __shfl_down(fc1, off);
        fc2 += __shfl_down(fc2, off);
        fc3 += __shfl_down(fc3, off);
    }
    if (lane == 0) {
        const float l0 = fc0 + b_fc[0], l1 = fc1 + b_fc[1];
        const float l2 = fc2 + b_fc[2], l3 = fc3 + b_fc[3];
        const float m  = fmaxf(fmaxf(l0, l1), fmaxf(l2, l3));
        const float e0 = __expf(l0 - m), e1 = __expf(l1 - m);
        const float e2 = __expf(l2 - m), e3 = __expf(l3 - m);
        const float is = __builtin_amdgcn_rcpf(e0 + e1 + e2 + e3);
        float4 o; o.x = e0 * is; o.y = e1 * is; o.z = e2 * is; o.w = e3 * is;
        *(float4*)(out + r * NCLS) = o;
    }
}

extern "C" void kernel_launch(void* const* d_in, const int* in_sizes, int n_in,
                              void* d_out, int out_size, void* d_ws, size_t ws_size,
                              hipStream_t stream) {
    const float* x    = (const float*)d_in[0];
    const float* W_ih = (const float*)d_in[1];
    const float* W_hh = (const float*)d_in[2];
    const float* b_ih = (const float*)d_in[3];
    const float* b_hh = (const float*)d_in[4];
    const float* W_fc = (const float*)d_in[5];
    const float* b_fc = (const float*)d_in[6];
    float* out = (float*)d_out;

    lstm_fused<<<BB, 64, 0, stream>>>(x, W_ih, W_hh, b_ih, b_hh, W_fc, b_fc, out);
}

// Round 12
// 623.272 us; speedup vs baseline: 2.0560x; 2.0560x over previous
//
#include <hip/hip_runtime.h>

// Problem constants
#define BB   512
#define CC   22
#define TT   1000
#define HH   64
#define NCLS 4
#define FCW  (TT * HH)       // 64000: W_fc row length
#define TBX  200             // t-tile per xproj block (5 tiles) -- R13 exact
#define TCF  250             // rec: t-chunk for batched FC / h history

typedef _Float16 f16;
typedef __attribute__((ext_vector_type(2))) _Float16 h2;

__device__ __forceinline__ float sigm(float x) {
    float e = __expf(-x);
    return __builtin_amdgcn_rcpf(1.0f + e);
}
__device__ __forceinline__ float tanh_(float x) {
    float e = __expf(-2.0f * fabsf(x));   // (0,1], no overflow
    float r = (1.0f - e) * __builtin_amdgcn_rcpf(1.0f + e);
    return copysignf(r, x);
}
__device__ __forceinline__ h2 u2h(unsigned u) {
    union { unsigned u; h2 h; } c; c.u = u; return c.h;
}
__device__ __forceinline__ unsigned h2u(h2 h) {
    union { unsigned u; h2 h; } c; c.h = h; return c.u;
}
__device__ __forceinline__ unsigned pack2(float a, float b) {
    union { unsigned u; h2 h; } c;
    c.h = h2{(f16)a, (f16)b};
    return c.u;
}

// ---------------------------------------------------------------------------
// R16 kernel 1: x-projection -- R13's exact version (best-measured total).
// ---------------------------------------------------------------------------
__global__ __launch_bounds__(256) void xproj(
    const float* __restrict__ x,     // [B, C, T]
    const float* __restrict__ W_ih,  // [4H, C]
    const float* __restrict__ b_ih,  // [4H]
    const float* __restrict__ b_hh,  // [4H]
    uint2* __restrict__ xp)          // [B*T*64] uint2
{
    __shared__ __align__(16) h2 xt[TBX][12];   // 9.6 KB

    const int tid = threadIdx.x;
    const int t0  = blockIdx.x * TBX;
    const int b   = blockIdx.y;
    const int hid = tid & 63;
    const int tsub = tid >> 6;       // 4 t-phases

    if (tid < TBX) {
        const float* gx = x + (size_t)b * (CC * TT) + t0 + tid;
        union { h2 h[12]; uint4 q[3]; } U;
        #pragma unroll
        for (int k = 0; k < 11; ++k)
            U.h[k] = h2{(f16)gx[(2 * k) * TT], (f16)gx[(2 * k + 1) * TT]};
        U.h[11] = h2{(f16)0.0f, (f16)0.0f};
        uint4* dst = (uint4*)&xt[tid][0];
        dst[0] = U.q[0]; dst[1] = U.q[1]; dst[2] = U.q[2];
    }

    unsigned wih[4][11];
    float bias[4];
    #pragma unroll
    for (int g = 0; g < 4; ++g) {
        const float* wi = W_ih + (g * HH + hid) * CC;
        #pragma unroll
        for (int k = 0; k < 11; ++k)
            wih[g][k] = h2u(h2{(f16)wi[2 * k], (f16)wi[2 * k + 1]});
        bias[g] = b_ih[g * HH + hid] + b_hh[g * HH + hid];
    }
    __syncthreads();

    uint2* op = xp + ((size_t)b * TT + t0) * 64 + hid;
    for (int t = tsub; t < TBX; t += 4) {
        union { uint4 q[3]; h2 h[12]; } X;
        const uint4* xr = (const uint4*)&xt[t][0];   // broadcast b128
        X.q[0] = xr[0]; X.q[1] = xr[1]; X.q[2] = xr[2];
        float a0 = bias[0], a1 = bias[1], a2 = bias[2], a3 = bias[3];
        #pragma unroll
        for (int k = 0; k < 11; ++k) {
            a0 = __builtin_amdgcn_fdot2(X.h[k], u2h(wih[0][k]), a0, false);
            a1 = __builtin_amdgcn_fdot2(X.h[k], u2h(wih[1][k]), a1, false);
            a2 = __builtin_amdgcn_fdot2(X.h[k], u2h(wih[2][k]), a2, false);
            a3 = __builtin_amdgcn_fdot2(X.h[k], u2h(wih[3][k]), a3, false);
        }
        op[(size_t)t * 64] = uint2{pack2(a0, a1), pack2(a2, a3)};
    }
}

// ---------------------------------------------------------------------------
// R16 kernel 2: R13's rec core with the FC tax removed.
// R15 post-mortem re-audit of R13's 1230 cyc/step: the chunk-end FC loop was
// NOT unrolled -> 250 serially latency-exposed L2/L3-hit loads (~200-400cyc
// each) ~= 250-300 cyc/step hidden tax. With that, R13's ledger closes
// (600 issue + ~330 step stall + ~300 FC) -- no mystery term.
// Changes vs R13 (surgical, serial loop body untouched):
//  1. FC loop unrolled x8 with explicit load-then-use phases (32 loads in
//     flight; latency amortized 8x -> ~40-60 cyc/step equivalent).
//  2. Serial loop split: main body clamp-free with walking xp pointer
//     (kills per-step mul+cmp+cndmask), 3-step clamped tail.
// ---------------------------------------------------------------------------
__global__ __attribute__((amdgpu_waves_per_eu(1, 1)))
__launch_bounds__(64) void lstm_rec(
    const uint2* __restrict__ xp,    // [B, T, 64] uint2 (4 f16 gates)
    const float* __restrict__ W_hh,  // [4H, H]
    const float* __restrict__ W_fc,  // [NCLS, T*H]
    const float* __restrict__ b_fc,  // [NCLS]
    float* __restrict__ out)         // [B, NCLS]
{
    __shared__ __align__(16) f16 hst[TCF][HH];   // 32 KB: h history + broadcast

    const int lane = threadIdx.x;    // hidden unit
    const int r    = blockIdx.x;     // batch row

    // per-lane recurrent weights (128 VGPR), pinned resident
    unsigned whh[4][32];
    #pragma unroll
    for (int g = 0; g < 4; ++g) {
        const float* wr = W_hh + (g * HH + lane) * HH;
        #pragma unroll
        for (int k = 0; k < 32; ++k)
            whh[g][k] = h2u(h2{(f16)wr[2 * k], (f16)wr[2 * k + 1]});
    }
    #pragma unroll
    for (int g = 0; g < 4; ++g)
        #pragma unroll
        for (int k = 0; k < 32; ++k) asm volatile("" : "+v"(whh[g][k]));

    hst[TCF - 1][lane] = (f16)0.0f;  // h_0 (read by step tt=0 as "prev row")
    float c = 0.0f;
    float fc0 = 0.f, fc1 = 0.f, fc2 = 0.f, fc3 = 0.f;
    const uint2* px = xp + (size_t)r * TT * HH + lane;

    // 3-deep xp pipeline (6 VGPRs) + walking prefetch pointer
    uint2 xvA = px[0];
    uint2 xvB = px[HH];
    uint2 xvC = px[2 * HH];
    const uint2* pxw = px + 3 * HH;  // points at step t+3 for t = 0

    for (int chunk = 0; chunk < 4; ++chunk) {
        const int T0 = chunk * TCF;
        const int tmax = (chunk == 3) ? (TCF - 3) : TCF;   // clamp-free range

        // ---- main serial body: clamp-free prefetch via walking pointer ----
        for (int tt = 0; tt < tmax; ++tt) {
            const uint2 xvN = *pxw;  pxw += HH;

            const int pr = (tt == 0) ? TCF - 1 : tt - 1;
            union { uint4 q[8]; h2 h[32]; } H;
            const uint4* hr = (const uint4*)&hst[pr][0];
            #pragma unroll
            for (int i = 0; i < 8; ++i) H.q[i] = hr[i];

            const h2 pif = u2h(xvA.x), pgo = u2h(xvA.y);
            float a0 = (float)pif[0], a1 = (float)pif[1];
            float a2 = (float)pgo[0], a3 = (float)pgo[1];
            #pragma unroll
            for (int k = 0; k < 32; ++k) {
                a0 = __builtin_amdgcn_fdot2(H.h[k], u2h(whh[0][k]), a0, false);
                a1 = __builtin_amdgcn_fdot2(H.h[k], u2h(whh[1][k]), a1, false);
                a2 = __builtin_amdgcn_fdot2(H.h[k], u2h(whh[2][k]), a2, false);
                a3 = __builtin_amdgcn_fdot2(H.h[k], u2h(whh[3][k]), a3, false);
            }

            const float iv = sigm(a0), fv = sigm(a1);
            const float gv = tanh_(a2), ov = sigm(a3);
            c = fv * c + iv * gv;
            const float h = ov * tanh_(c);

            hst[tt][lane] = (f16)h;
            xvA = xvB; xvB = xvC; xvC = xvN;
        }
        // ---- clamped tail (last chunk only: steps 997..999) ----
        for (int tt = tmax; tt < TCF; ++tt) {
            const int pr = tt - 1;   // tmax>=1 in tail chunk
            union { uint4 q[8]; h2 h[32]; } H;
            const uint4* hr = (const uint4*)&hst[pr][0];
            #pragma unroll
            for (int i = 0; i < 8; ++i) H.q[i] = hr[i];

            const h2 pif = u2h(xvA.x), pgo = u2h(xvA.y);
            float a0 = (float)pif[0], a1 = (float)pif[1];
            float a2 = (float)pgo[0], a3 = (float)pgo[1];
            #pragma unroll
            for (int k = 0; k < 32; ++k) {
                a0 = __builtin_amdgcn_fdot2(H.h[k], u2h(whh[0][k]), a0, false);
                a1 = __builtin_amdgcn_fdot2(H.h[k], u2h(whh[1][k]), a1, false);
                a2 = __builtin_amdgcn_fdot2(H.h[k], u2h(whh[2][k]), a2, false);
                a3 = __builtin_amdgcn_fdot2(H.h[k], u2h(whh[3][k]), a3, false);
            }
            const float iv = sigm(a0), fv = sigm(a1);
            const float gv = tanh_(a2), ov = sigm(a3);
            c = fv * c + iv * gv;
            const float h = ov * tanh_(c);
            hst[tt][lane] = (f16)h;
            xvA = xvB; xvB = xvC;    // xvC becomes stale; unused past end
        }

        // ---- chunk-end batched FC: unrolled x8, load-then-use phases ----
        const float* w0 = W_fc + 0 * FCW + (size_t)T0 * HH + lane;
        const float* w1 = W_fc + 1 * FCW + (size_t)T0 * HH + lane;
        const float* w2 = W_fc + 2 * FCW + (size_t)T0 * HH + lane;
        const float* w3 = W_fc + 3 * FCW + (size_t)T0 * HH + lane;
        for (int tb = 0; tb < TCF - 2; tb += 8) {    // 248 = 31 batches of 8
            float wl0[8], wl1[8], wl2[8], wl3[8];
            #pragma unroll
            for (int u = 0; u < 8; ++u) {
                const size_t o = (size_t)(tb + u) * HH;
                wl0[u] = w0[o]; wl1[u] = w1[o]; wl2[u] = w2[o]; wl3[u] = w3[o];
            }
            #pragma unroll
            for (int u = 0; u < 8; ++u) {
                const float hv = (float)hst[tb + u][lane];
                fc0 += hv * wl0[u]; fc1 += hv * wl1[u];
                fc2 += hv * wl2[u]; fc3 += hv * wl3[u];
            }
        }
        #pragma unroll
        for (int tt = TCF - 2; tt < TCF; ++tt) {     // tail 2
            const size_t o = (size_t)tt * HH;
            const float hv = (float)hst[tt][lane];
            fc0 += hv * w0[o]; fc1 += hv * w1[o];
            fc2 += hv * w2[o]; fc3 += hv * w3[o];
        }
    }

    // FC reduce over hid (wave shuffle) + softmax
    #pragma unroll
    for (int off = 32; off; off >>= 1) {
        fc0 += __shfl_down(fc0, off);
        fc1 += __shfl_down(fc1, off);
        fc2 += __shfl_down(fc2, off);
        fc3 += __shfl_down(fc3, off);
    }
    if (lane == 0) {
        const float l0 = fc0 + b_fc[0], l1 = fc1 + b_fc[1];
        const float l2 = fc2 + b_fc[2], l3 = fc3 + b_fc[3];
        const float m  = fmaxf(fmaxf(l0, l1), fmaxf(l2, l3));
        const float e0 = __expf(l0 - m), e1 = __expf(l1 - m);
        const float e2 = __expf(l2 - m), e3 = __expf(l3 - m);
        const float is = __builtin_amdgcn_rcpf(e0 + e1 + e2 + e3);
        float4 o; o.x = e0 * is; o.y = e1 * is; o.z = e2 * is; o.w = e3 * is;
        *(float4*)(out + r * NCLS) = o;
    }
}

// ---------------------------------------------------------------------------
// Fallback: self-contained single kernel (R4 structure), used only if the
// workspace can't hold xp (262 MB).
// ---------------------------------------------------------------------------
#define TC   250
#define NCHUNK (TT / TC)
#define XROW 12

__global__ __attribute__((amdgpu_waves_per_eu(1, 1)))
__launch_bounds__(64) void lstm_fb(
    const float* __restrict__ x, const float* __restrict__ W_ih,
    const float* __restrict__ W_hh, const float* __restrict__ b_ih,
    const float* __restrict__ b_hh, const float* __restrict__ W_fc,
    const float* __restrict__ b_fc, float* __restrict__ out)
{
    __shared__ __align__(16) h2  xs[TC][XROW];
    __shared__ __align__(16) f16 hbuf[HH];

    const int lane = threadIdx.x;
    const int r    = blockIdx.x;

    unsigned whh[4][32];
    unsigned wih[4][11];
    float bias[4];
    #pragma unroll
    for (int g = 0; g < 4; ++g) {
        const int row = g * HH + lane;
        const float* wr = W_hh + row * HH;
        #pragma unroll
        for (int k = 0; k < 32; ++k)
            whh[g][k] = h2u(h2{(f16)wr[2 * k], (f16)wr[2 * k + 1]});
        const float* wi = W_ih + row * CC;
        #pragma unroll
        for (int k = 0; k < 11; ++k)
            wih[g][k] = h2u(h2{(f16)wi[2 * k], (f16)wi[2 * k + 1]});
        bias[g] = b_ih[row] + b_hh[row];
    }
    #pragma unroll
    for (int g = 0; g < 4; ++g) {
        #pragma unroll
        for (int k = 0; k < 32; ++k) asm volatile("" : "+v"(whh[g][k]));
        #pragma unroll
        for (int k = 0; k < 11; ++k) asm volatile("" : "+v"(wih[g][k]));
        asm volatile("" : "+v"(bias[g]));
    }

    hbuf[lane] = (f16)0.0f;
    float c = 0.0f;
    float fc0 = 0.f, fc1 = 0.f, fc2 = 0.f, fc3 = 0.f;
    const float* p0 = W_fc + 0 * FCW + lane;
    const float* p1 = W_fc + 1 * FCW + lane;
    const float* p2 = W_fc + 2 * FCW + lane;
    const float* p3 = W_fc + 3 * FCW + lane;
    const float* xrow = x + (size_t)r * (CC * TT);

    for (int chunk = 0; chunk < NCHUNK; ++chunk) {
        for (int tb = 0; tb < TC; tb += 64) {
            const int t = tb + lane;
            if (t < TC) {
                const float* gx = xrow + chunk * TC + t;
                union { h2 h[XROW]; uint4 q[3]; } U;
                #pragma unroll
                for (int k = 0; k < 11; ++k)
                    U.h[k] = h2{(f16)gx[(2 * k) * TT], (f16)gx[(2 * k + 1) * TT]};
                U.h[11] = h2{(f16)0.0f, (f16)0.0f};
                uint4* dst = (uint4*)&xs[t][0];
                dst[0] = U.q[0]; dst[1] = U.q[1]; dst[2] = U.q[2];
            }
        }
        for (int tt = 0; tt < TC; ++tt) {
            union { uint4 q[8]; h2 h[32]; } H;
            const uint4* hr = (const uint4*)hbuf;
            #pragma unroll
            for (int i = 0; i < 8; ++i) H.q[i] = hr[i];
            union { uint4 q[3]; h2 h[XROW]; } X;
            const uint4* xr = (const uint4*)&xs[tt][0];
            X.q[0] = xr[0]; X.q[1] = xr[1]; X.q[2] = xr[2];
            float w0 = *p0, w1 = *p1, w2 = *p2, w3 = *p3;
            p0 += HH; p1 += HH; p2 += HH; p3 += HH;
            float a0 = bias[0], a1 = bias[1], a2 = bias[2], a3 = bias[3];
            #pragma unroll
            for (int k = 0; k < 11; ++k) {
                a0 = __builtin_amdgcn_fdot2(X.h[k], u2h(wih[0][k]), a0, false);
                a1 = __builtin_amdgcn_fdot2(X.h[k], u2h(wih[1][k]), a1, false);
                a2 = __builtin_amdgcn_fdot2(X.h[k], u2h(wih[2][k]), a2, false);
                a3 = __builtin_amdgcn_fdot2(X.h[k], u2h(wih[3][k]), a3, false);
            }
            #pragma unroll
            for (int k = 0; k < 32; ++k) {
                a0 = __builtin_amdgcn_fdot2(H.h[k], u2h(whh[0][k]), a0, false);
                a1 = __builtin_amdgcn_fdot2(H.h[k], u2h(whh[1][k]), a1, false);
                a2 = __builtin_amdgcn_fdot2(H.h[k], u2h(whh[2][k]), a2, false);
                a3 = __builtin_amdgcn_fdot2(H.h[k], u2h(whh[3][k]), a3, false);
            }
            const float iv = sigm(a0), fv = sigm(a1);
            const float gv = tanh_(a2), ov = sigm(a3);
            c = fv * c + iv * gv;
            const float h = ov * tanh_(c);
            fc0 += h * w0; fc1 += h * w1; fc2 += h * w2; fc3 += h * w3;
            hbuf[lane] = (f16)h;
        }
    }
    #pragma unroll
    for (int off = 32; off; off >>= 1) {
        fc0 += __shfl_down(fc0, off);
        fc1 += __shfl_down(fc1, off);
        fc2 += __shfl_down(fc2, off);
        fc3 += __shfl_down(fc3, off);
    }
    if (lane == 0) {
        const float l0 = fc0 + b_fc[0], l1 = fc1 + b_fc[1];
        const float l2 = fc2 + b_fc[2], l3 = fc3 + b_fc[3];
        const float m  = fmaxf(fmaxf(l0, l1), fmaxf(l2, l3));
        const float e0 = __expf(l0 - m), e1 = __expf(l1 - m);
        const float e2 = __expf(l2 - m), e3 = __expf(l3 - m);
        const float is = __builtin_amdgcn_rcpf(e0 + e1 + e2 + e3);
        float4 o; o.x = e0 * is; o.y = e1 * is; o.z = e2 * is; o.w = e3 * is;
        *(float4*)(out + r * NCLS) = o;
    }
}

extern "C" void kernel_launch(void* const* d_in, const int* in_sizes, int n_in,
                              void* d_out, int out_size, void* d_ws, size_t ws_size,
                              hipStream_t stream) {
    const float* x    = (const float*)d_in[0];
    const float* W_ih = (const float*)d_in[1];
    const float* W_hh = (const float*)d_in[2];
    const float* b_ih = (const float*)d_in[3];
    const float* b_hh = (const float*)d_in[4];
    const float* W_fc = (const float*)d_in[5];
    const float* b_fc = (const float*)d_in[6];
    float* out = (float*)d_out;

    const size_t need = (size_t)BB * TT * HH * 4 * sizeof(f16);   // 262.1 MB
    if (d_ws != nullptr && ws_size >= need) {
        uint2* xp = (uint2*)d_ws;
        xproj<<<dim3(TT / TBX, BB), 256, 0, stream>>>(x, W_ih, b_ih, b_hh, xp);
        lstm_rec<<<BB, 64, 0, stream>>>(xp, W_hh, W_fc, b_fc, out);
    } else {
        lstm_fb<<<BB, 64, 0, stream>>>(x, W_ih, W_hh, b_ih, b_hh, W_fc, b_fc, out);
    }
}

// Round 13
// 599.626 us; speedup vs baseline: 2.1370x; 1.0394x over previous
//
#include <hip/hip_runtime.h>

// Problem constants
#define BB   512
#define CC   22
#define TT   1000
#define HH   64
#define NCLS 4
#define FCW  (TT * HH)       // 64000: W_fc row length
#define TCF  250             // t-chunk: xs staging + h history + batched FC
#define XROW 12              // h2 slots per xs row (48B rows: 0 conflicts, R4)

typedef _Float16 f16;
typedef __attribute__((ext_vector_type(2))) _Float16 h2;

__device__ __forceinline__ float sigm(float x) {
    float e = __expf(-x);
    return __builtin_amdgcn_rcpf(1.0f + e);
}
__device__ __forceinline__ float tanh_(float x) {
    float e = __expf(-2.0f * fabsf(x));   // (0,1], no overflow
    float r = (1.0f - e) * __builtin_amdgcn_rcpf(1.0f + e);
    return copysignf(r, x);
}
__device__ __forceinline__ h2 u2h(unsigned u) {
    union { unsigned u; h2 h; } c; c.u = u; return c.h;
}
__device__ __forceinline__ unsigned h2u(h2 h) {
    union { unsigned u; h2 h; } c; c.h = h; return c.u;
}

// xp for one x-row from LDS: 3 broadcast b128 reads + 44 fdot2, accumulators
// init from folded bias. Macro (not function) so wih[][] stays compile-time
// indexed -> registers (rule: runtime-indexed arrays go to scratch).
#define XP_COMPUTE(TROW, O0, O1, O2, O3) do {                                  \
    union { uint4 q[3]; h2 h[XROW]; } Xu_;                                     \
    const uint4* xr_ = (const uint4*)&xs[(TROW)][0];                           \
    Xu_.q[0] = xr_[0]; Xu_.q[1] = xr_[1]; Xu_.q[2] = xr_[2];                   \
    O0 = bias[0]; O1 = bias[1]; O2 = bias[2]; O3 = bias[3];                    \
    _Pragma("unroll")                                                          \
    for (int k_ = 0; k_ < 11; ++k_) {                                          \
        O0 = __builtin_amdgcn_fdot2(Xu_.h[k_], u2h(wih[0][k_]), O0, false);    \
        O1 = __builtin_amdgcn_fdot2(Xu_.h[k_], u2h(wih[1][k_]), O1, false);    \
        O2 = __builtin_amdgcn_fdot2(Xu_.h[k_], u2h(wih[2][k_]), O2, false);    \
        O3 = __builtin_amdgcn_fdot2(Xu_.h[k_], u2h(wih[3][k_]), O3, false);    \
    }                                                                          \
} while (0)

// ---------------------------------------------------------------------------
// R17: single fused kernel = R16's serial core + INLINE one-step-ahead x-dots.
//
// Ledger: R16 rec = 1165 cyc/step = ~770 busy (fdot2 ~4-5cyc/wave64) + ~400
// stall (h DS round-trip + trans chains). The two-kernel split still paid
// ~137us xproj wall + 262MB xp HBM roundtrip while the rec wave idled 34%.
// Fix: during step t, compute xp[t+1] = bias + W_ih . x[t+1] (44 fdot2, reads
// only LDS-staged x) into SEPARATE registers, placed between the H-read issue
// and the H-dot use. Unlike R4 (which chained x-dots into the same
// accumulators, serializing them), these are independent of h -> the
// scheduler drops them into the ~400cyc stall window. FC stays chunk-end
// batched (R16). No workspace, no second dispatch, xp never touches HBM.
//
// Zero barriers: one wave per block; xs/hst are own-wave data (in-order DS).
// ---------------------------------------------------------------------------
__global__ __launch_bounds__(64, 1) void lstm_one(
    const float* __restrict__ x,     // [B, C, T]
    const float* __restrict__ W_ih,  // [4H, C]
    const float* __restrict__ W_hh,  // [4H, H]
    const float* __restrict__ b_ih,  // [4H]
    const float* __restrict__ b_hh,  // [4H]
    const float* __restrict__ W_fc,  // [NCLS, T*H]
    const float* __restrict__ b_fc,  // [NCLS]
    float* __restrict__ out)         // [B, NCLS]
{
    __shared__ __align__(16) h2  xs[TCF][XROW];   // 12 KB: x chunk (48B rows)
    __shared__ __align__(16) f16 hst[TCF][HH];    // 32 KB: h history + broadcast

    const int lane = threadIdx.x;    // hidden unit
    const int r    = blockIdx.x;     // batch row

    // ---- per-lane weights into registers (one-time), pinned ----
    unsigned whh[4][32];      // recurrent rows: 128 regs
    unsigned wih[4][11];      // input rows: 44 regs
    float    bias[4];
    #pragma unroll
    for (int g = 0; g < 4; ++g) {
        const int row = g * HH + lane;
        const float* wr = W_hh + row * HH;
        #pragma unroll
        for (int k = 0; k < 32; ++k)
            whh[g][k] = h2u(h2{(f16)wr[2 * k], (f16)wr[2 * k + 1]});
        const float* wi = W_ih + row * CC;
        #pragma unroll
        for (int k = 0; k < 11; ++k)
            wih[g][k] = h2u(h2{(f16)wi[2 * k], (f16)wi[2 * k + 1]});
        bias[g] = b_ih[row] + b_hh[row];
    }
    #pragma unroll
    for (int g = 0; g < 4; ++g) {
        #pragma unroll
        for (int k = 0; k < 32; ++k) asm volatile("" : "+v"(whh[g][k]));
        #pragma unroll
        for (int k = 0; k < 11; ++k) asm volatile("" : "+v"(wih[g][k]));
        asm volatile("" : "+v"(bias[g]));
    }

    hst[TCF - 1][lane] = (f16)0.0f;  // h_0 (read by chunk 0, tt=0 as prev row)
    float c = 0.0f;
    float fc0 = 0.f, fc1 = 0.f, fc2 = 0.f, fc3 = 0.f;
    const float* xrow = x + (size_t)r * (CC * TT);

    for (int chunk = 0; chunk < 4; ++chunk) {
        const int T0 = chunk * TCF;

        // ---- stage x chunk into LDS (own wave, off-chain; R4 pattern) ----
        for (int tb = 0; tb < TCF; tb += 64) {
            const int t = tb + lane;
            if (t < TCF) {
                const float* gx = xrow + T0 + t;   // stride TT per channel
                union { h2 h[XROW]; uint4 q[3]; } U;
                #pragma unroll
                for (int k = 0; k < 11; ++k)
                    U.h[k] = h2{(f16)gx[(2 * k) * TT], (f16)gx[(2 * k + 1) * TT]};
                U.h[11] = h2{(f16)0.0f, (f16)0.0f};
                uint4* dst = (uint4*)&xs[t][0];
                dst[0] = U.q[0]; dst[1] = U.q[1]; dst[2] = U.q[2];
            }
        }

        // xp for the chunk's first step (prologue)
        float xpc0, xpc1, xpc2, xpc3;
        XP_COMPUTE(0, xpc0, xpc1, xpc2, xpc3);

        // ---- serial recurrence: consume xp[tt], compute xp[tt+1] ----
        for (int tt = 0; tt < TCF; ++tt) {
            const int pr = (tt == 0) ? TCF - 1 : tt - 1;

            // issue h broadcast reads first (8 same-address b128)
            union { uint4 q[8]; h2 h[32]; } H;
            const uint4* hr = (const uint4*)&hst[pr][0];
            #pragma unroll
            for (int i = 0; i < 8; ++i) H.q[i] = hr[i];

            // next step's xp: independent of H -> fills the DS-read latency
            float xn0, xn1, xn2, xn3;
            if (tt != TCF - 1) {
                XP_COMPUTE(tt + 1, xn0, xn1, xn2, xn3);
            } else {
                xn0 = xn1 = xn2 = xn3 = 0.0f;
            }

            // gate dots over h (128 fdot2), accumulators init from xp[tt]
            float a0 = xpc0, a1 = xpc1, a2 = xpc2, a3 = xpc3;
            #pragma unroll
            for (int k = 0; k < 32; ++k) {
                a0 = __builtin_amdgcn_fdot2(H.h[k], u2h(whh[0][k]), a0, false);
                a1 = __builtin_amdgcn_fdot2(H.h[k], u2h(whh[1][k]), a1, false);
                a2 = __builtin_amdgcn_fdot2(H.h[k], u2h(whh[2][k]), a2, false);
                a3 = __builtin_amdgcn_fdot2(H.h[k], u2h(whh[3][k]), a3, false);
            }

            // lane-local LSTM update
            const float iv = sigm(a0), fv = sigm(a1);
            const float gv = tanh_(a2), ov = sigm(a3);
            c = fv * c + iv * gv;
            const float h = ov * tanh_(c);

            // publish h (history row tt doubles as broadcast source for tt+1)
            hst[tt][lane] = (f16)h;

            // rotate xp pipeline
            xpc0 = xn0; xpc1 = xn1; xpc2 = xn2; xpc3 = xn3;
        }

        // ---- chunk-end batched FC: unrolled x8, load-then-use (R16) ----
        const float* w0 = W_fc + 0 * FCW + (size_t)T0 * HH + lane;
        const float* w1 = W_fc + 1 * FCW + (size_t)T0 * HH + lane;
        const float* w2 = W_fc + 2 * FCW + (size_t)T0 * HH + lane;
        const float* w3 = W_fc + 3 * FCW + (size_t)T0 * HH + lane;
        for (int tb = 0; tb < TCF - 2; tb += 8) {    // 248 = 31 batches of 8
            float wl0[8], wl1[8], wl2[8], wl3[8];
            #pragma unroll
            for (int u = 0; u < 8; ++u) {
                const size_t o = (size_t)(tb + u) * HH;
                wl0[u] = w0[o]; wl1[u] = w1[o]; wl2[u] = w2[o]; wl3[u] = w3[o];
            }
            #pragma unroll
            for (int u = 0; u < 8; ++u) {
                const float hv = (float)hst[tb + u][lane];
                fc0 += hv * wl0[u]; fc1 += hv * wl1[u];
                fc2 += hv * wl2[u]; fc3 += hv * wl3[u];
            }
        }
        #pragma unroll
        for (int tt = TCF - 2; tt < TCF; ++tt) {     // tail 2
            const size_t o = (size_t)tt * HH;
            const float hv = (float)hst[tt][lane];
            fc0 += hv * w0[o]; fc1 += hv * w1[o];
            fc2 += hv * w2[o]; fc3 += hv * w3[o];
        }
    }

    // ---- FC reduce over hid (wave shuffle) + softmax ----
    #pragma unroll
    for (int off = 32; off; off >>= 1) {
        fc0 += __shfl_down(fc0, off);
        fc1 += __shfl_down(fc1, off);
        fc2 += __shfl_down(fc2, off);
        fc3 += __shfl_down(fc3, off);
    }
    if (lane == 0) {
        const float l0 = fc0 + b_fc[0], l1 = fc1 + b_fc[1];
        const float l2 = fc2 + b_fc[2], l3 = fc3 + b_fc[3];
        const float m  = fmaxf(fmaxf(l0, l1), fmaxf(l2, l3));
        const float e0 = __expf(l0 - m), e1 = __expf(l1 - m);
        const float e2 = __expf(l2 - m), e3 = __expf(l3 - m);
        const float is = __builtin_amdgcn_rcpf(e0 + e1 + e2 + e3);
        float4 o; o.x = e0 * is; o.y = e1 * is; o.z = e2 * is; o.w = e3 * is;
        *(float4*)(out + r * NCLS) = o;
    }
}

extern "C" void kernel_launch(void* const* d_in, const int* in_sizes, int n_in,
                              void* d_out, int out_size, void* d_ws, size_t ws_size,
                              hipStream_t stream) {
    const float* x    = (const float*)d_in[0];
    const float* W_ih = (const float*)d_in[1];
    const float* W_hh = (const float*)d_in[2];
    const float* b_ih = (const float*)d_in[3];
    const float* b_hh = (const float*)d_in[4];
    const float* W_fc = (const float*)d_in[5];
    const float* b_fc = (const float*)d_in[6];
    float* out = (float*)d_out;

    lstm_one<<<BB, 64, 0, stream>>>(x, W_ih, W_hh, b_ih, b_hh, W_fc, b_fc, out);
}